// Round 9
// baseline (30475.015 us; speedup 1.0000x reference)
//
#include <hip/hip_runtime.h>
#include <stdint.h>

#define T_SEQ 2048
#define NB 32
#define NH 1024
#define HH (NH*NH)
#define HIST_ELEMS ((size_t)T_SEQ*NB*NH)
#define TEAM 32
#define SLOTB (NB*NH*4)          // one parity slot of tagged state: 128 KiB

typedef __attribute__((ext_vector_type(8))) short bf16x8;
typedef __attribute__((ext_vector_type(4))) float f32x4;
typedef __attribute__((ext_vector_type(4))) int   i32x4;
typedef __attribute__((ext_vector_type(4))) short s16x4;

__device__ __forceinline__ unsigned short bf16rne(float f){
  union { float f; unsigned u; } v; v.f = f;
  unsigned u = v.u;
  return (unsigned short)((u + 0x7FFFu + ((u >> 16) & 1u)) >> 16);
}
__device__ __forceinline__ float bf16tof(unsigned short s){
  union { unsigned u; float f; } v; v.u = ((unsigned)s) << 16; return v.f;
}
__device__ __forceinline__ float fast_tanh(float x){
  float ax = fabsf(x);
  float e  = __expf(-2.0f*ax);
  float t  = (1.0f - e) / (1.0f + e);
  return copysignf(t, x);
}

__device__ __forceinline__ void st128_c(void* p, i32x4 v){
  asm volatile("global_store_dwordx4 %0, %1, off sc0 sc1" :: "v"(p), "v"(v) : "memory");
}

// single coherent dword probe (load+drain fused: spill-safe by construction)
__device__ __forceinline__ unsigned probe32(const void* p){
  unsigned d;
  asm volatile("global_load_dword %0, %1, off sc0 sc1\n\ts_waitcnt vmcnt(0)"
               : "=&v"(d) : "v"(p) : "memory");
  __builtin_amdgcn_sched_barrier(0);
  return d;
}

// unpack two x4-loads (8 tagged cols) -> one bf16x8 fragment; R5-PROVEN shift math.
__device__ __forceinline__ i32x4 pack_frag(const i32x4 a, const i32x4 b,
                                           unsigned rep, unsigned &bad){
  unsigned a0=(unsigned)a[0], a1=(unsigned)a[1], a2=(unsigned)a[2], a3=(unsigned)a[3];
  unsigned b0=(unsigned)b[0], b1=(unsigned)b[1], b2=(unsigned)b[2], b3=(unsigned)b[3];
  i32x4 f;
  f[0] = (int)((a0 >> 16) | (a1 & 0xFFFF0000u));
  f[1] = (int)((a2 >> 16) | (a3 & 0xFFFF0000u));
  f[2] = (int)((b0 >> 16) | (b1 & 0xFFFF0000u));
  f[3] = (int)((b2 >> 16) | (b3 & 0xFFFF0000u));
  bad |= ((a0 & 0xFFFFu) | (a1 << 16)) ^ rep;
  bad |= ((a2 & 0xFFFFu) | (a3 << 16)) ^ rep;
  bad |= ((b0 & 0xFFFFu) | (b1 << 16)) ^ rep;
  bad |= ((b2 & 0xFFFFu) | (b3 << 16)) ^ rep;
  return f;
}

// Fused 16-load + drain block (spill-safe: waitcnt inside the asm).
#define GATHER16(RB, FARR, REP, BAD)                                         \
  {                                                                          \
    i32x4 r0,r1,r2,r3,r4,r5,r6,r7,r8,r9,r10,r11,r12,r13,r14,r15;             \
    asm volatile(                                                            \
      "global_load_dwordx4 %0, %16, off sc0 sc1\n\t"                         \
      "global_load_dwordx4 %1, %16, off offset:16 sc0 sc1\n\t"               \
      "global_load_dwordx4 %2, %16, off offset:128 sc0 sc1\n\t"              \
      "global_load_dwordx4 %3, %16, off offset:144 sc0 sc1\n\t"              \
      "global_load_dwordx4 %4, %16, off offset:256 sc0 sc1\n\t"              \
      "global_load_dwordx4 %5, %16, off offset:272 sc0 sc1\n\t"              \
      "global_load_dwordx4 %6, %16, off offset:384 sc0 sc1\n\t"              \
      "global_load_dwordx4 %7, %16, off offset:400 sc0 sc1\n\t"              \
      "global_load_dwordx4 %8, %16, off offset:512 sc0 sc1\n\t"              \
      "global_load_dwordx4 %9, %16, off offset:528 sc0 sc1\n\t"              \
      "global_load_dwordx4 %10, %16, off offset:640 sc0 sc1\n\t"             \
      "global_load_dwordx4 %11, %16, off offset:656 sc0 sc1\n\t"             \
      "global_load_dwordx4 %12, %16, off offset:768 sc0 sc1\n\t"             \
      "global_load_dwordx4 %13, %16, off offset:784 sc0 sc1\n\t"             \
      "global_load_dwordx4 %14, %16, off offset:896 sc0 sc1\n\t"             \
      "global_load_dwordx4 %15, %16, off offset:912 sc0 sc1\n\t"             \
      "s_waitcnt vmcnt(0)"                                                   \
      : "=&v"(r0),"=&v"(r1),"=&v"(r2),"=&v"(r3),                             \
        "=&v"(r4),"=&v"(r5),"=&v"(r6),"=&v"(r7),                             \
        "=&v"(r8),"=&v"(r9),"=&v"(r10),"=&v"(r11),                           \
        "=&v"(r12),"=&v"(r13),"=&v"(r14),"=&v"(r15)                          \
      : "v"(RB) : "memory");                                                 \
    __builtin_amdgcn_sched_barrier(0);                                       \
    FARR[0] = pack_frag(r0,r1,REP,BAD);   FARR[1] = pack_frag(r2,r3,REP,BAD);   \
    FARR[2] = pack_frag(r4,r5,REP,BAD);   FARR[3] = pack_frag(r6,r7,REP,BAD);   \
    FARR[4] = pack_frag(r8,r9,REP,BAD);   FARR[5] = pack_frag(r10,r11,REP,BAD); \
    FARR[6] = pack_frag(r12,r13,REP,BAD); FARR[7] = pack_frag(r14,r15,REP,BAD); \
  }

// probe-wait (cheap 4B/lane spin) then validated gather; ALL caps per-use.
#define WAIT_GATHER(BASE, FARR, REP, TAG)                                    \
  {                                                                          \
    int pw = 0;                                                              \
    for (;;){                                                                \
      unsigned pr = probe32(BASE);                                           \
      if (__all((int)((pr & 0xFFFFu) == (TAG)))) break;                      \
      if (++pw > 8192) break;                                                \
      if (pw > 8) __builtin_amdgcn_s_sleep(1);                               \
    }                                                                        \
    int gt = 0;                                                              \
    for (;;){                                                                \
      unsigned bad = 0;                                                      \
      GATHER16(BASE,         FARR[0], REP, bad);                             \
      GATHER16(BASE + 65536, FARR[1], REP, bad);                             \
      if (__all((int)(bad == 0))) break;                                     \
      if (++gt > 1024) break;                                                \
      if (gt > 4) __builtin_amdgcn_s_sleep(1);                               \
    }                                                                        \
  }

// =====================================================================
// Kernel 1: pre0 = x @ Wih0^T + b_ih0 + b_hh0   (unchanged — validated)
// =====================================================================
__global__ __launch_bounds__(256)
void pre_gemm(const float* __restrict__ x,
              const float* __restrict__ Wih,
              const float* __restrict__ bih,
              const float* __restrict__ bhh,
              _Float16* __restrict__ pre0)
{
  __shared__ float As[128][36];
  const int tid  = threadIdx.x;
  const int lane = tid & 63;
  const int wave = tid >> 6;
  const int l15  = lane & 15;
  const int l4   = lane >> 4;
  const int n0   = blockIdx.x * 128;
  const int m0   = blockIdx.y * 128;
  const int qm   = wave >> 1;
  const int qn   = wave & 1;

  f32x4 acc[4][4];
  #pragma unroll
  for (int i = 0; i < 4; ++i)
    #pragma unroll
    for (int j = 0; j < 4; ++j) acc[i][j] = (f32x4){0.f,0.f,0.f,0.f};

  const int sr = tid >> 1;
  const int sh = tid & 1;
  const float* xrow = x + (size_t)(m0 + sr)*NH + sh*16;

  for (int kb = 0; kb < 32; ++kb){
    __syncthreads();
    {
      const float* src = xrow + kb*32;
      f32x4 v0 = *(const f32x4*)(src + 0);
      f32x4 v1 = *(const f32x4*)(src + 4);
      f32x4 v2 = *(const f32x4*)(src + 8);
      f32x4 v3 = *(const f32x4*)(src + 12);
      float* dst = &As[sr][sh*16];
      *(f32x4*)(dst + 0)  = v0;
      *(f32x4*)(dst + 4)  = v1;
      *(f32x4*)(dst + 8)  = v2;
      *(f32x4*)(dst + 12) = v3;
    }
    __syncthreads();

    bf16x8 ahi[4], alo[4];
    #pragma unroll
    for (int mt = 0; mt < 4; ++mt){
      const float* ap = &As[64*qm + 16*mt + l15][l4*8];
      #pragma unroll
      for (int j = 0; j < 8; ++j){
        float a = ap[j];
        unsigned short hb = bf16rne(a);
        ahi[mt][j] = (short)hb;
        alo[mt][j] = (short)bf16rne(a - bf16tof(hb));
      }
    }
    #pragma unroll
    for (int nf = 0; nf < 4; ++nf){
      const int c = n0 + 64*qn + 16*nf + l15;
      const float* wp = Wih + (size_t)c*NH + kb*32 + l4*8;
      bf16x8 bf;
      #pragma unroll
      for (int j = 0; j < 8; ++j) bf[j] = (short)bf16rne(wp[j]);
      #pragma unroll
      for (int mt = 0; mt < 4; ++mt){
        acc[mt][nf] = __builtin_amdgcn_mfma_f32_16x16x32_bf16(ahi[mt], bf, acc[mt][nf], 0,0,0);
        acc[mt][nf] = __builtin_amdgcn_mfma_f32_16x16x32_bf16(alo[mt], bf, acc[mt][nf], 0,0,0);
      }
    }
  }

  #pragma unroll
  for (int nf = 0; nf < 4; ++nf){
    const int c = n0 + 64*qn + 16*nf + l15;
    const float bv = bih[c] + bhh[c];
    #pragma unroll
    for (int mt = 0; mt < 4; ++mt){
      const int mb = m0 + 64*qm + 16*mt + l4*4;
      #pragma unroll
      for (int j = 0; j < 4; ++j)
        pre0[(size_t)(mb + j)*NH + c] = (_Float16)(acc[mt][nf][j] + bv);
    }
  }
}

// =====================================================================
// Kernel 2: 32-WG persistent recurrence, self-validating tagged state
// (R5-proven protocol) + spill-safe fused-asm gathers + PER-USE retry
// caps (the R4/R7/R8 bug was a cumulative never-reset budget: once
// exhausted, every later gather accepted garbage). Probe-wait makes
// the waiting cheap (4B/lane spin, not 8KB/WG re-gathers).
// =====================================================================
__global__ __launch_bounds__(256, 1)
void rnn_seq(const float* __restrict__ h0in,
             const float* __restrict__ Wih,
             const float* __restrict__ Whh,
             const float* __restrict__ bih,
             const float* __restrict__ bhh,
             const _Float16* __restrict__ pre0,
             float* __restrict__ dout,
             char* __restrict__ ws)
{
  const int tid  = threadIdx.x;
  const int lane = tid & 63;
  const int wave = tid >> 6;
  const int l15  = lane & 15;
  const int l4   = lane >> 4;
  const int rank = blockIdx.x;     // 0..31
  const int c0   = rank * 32;

  char* H0 = ws + 4096;            // [2 parity][32 b][1024 c] tagged u32
  char* H1 = ws + 4096 + 2*SLOTB;

  // ---- static weight A-fragments: [0]=Whh0 [1]=Wih1 [2]=Whh1 (proven) ----
  bf16x8 wA[3][2][8];
  #pragma unroll
  for (int cf = 0; cf < 2; ++cf){
    const size_t row = (size_t)(c0 + cf*16 + l15) * NH;
    const float* s0 = Whh + row;
    const float* s1 = Wih + HH + row;
    const float* s2 = Whh + HH + row;
    #pragma unroll
    for (int s = 0; s < 8; ++s){
      const int k = wave*256 + s*32 + l4*8;
      #pragma unroll
      for (int j = 0; j < 8; ++j){
        wA[0][cf][s][j] = (short)bf16rne(s0[k+j]);
        wA[1][cf][s][j] = (short)bf16rne(s1[k+j]);
        wA[2][cf][s][j] = (short)bf16rne(s2[k+j]);
      }
    }
  }

  // ---- epilogue mapping: thread -> (batch, 4-col block), both layers ----
  const int eb   = tid >> 3;       // 0..31
  const int ecb  = tid & 7;        // 0..7
  const int ecol = c0 + ecb*4;

  f32x4 bias1;
  #pragma unroll
  for (int j = 0; j < 4; ++j)
    bias1[j] = bih[NH + ecol + j] + bhh[NH + ecol + j];

  // ---- initial state h(-1): tag = 1, parity-1 slots ----
  {
    const float* hs0 = h0in + (size_t)eb*NH + ecol;
    const float* hs1 = h0in + (size_t)NB*NH + (size_t)eb*NH + ecol;
    i32x4 p0, p1;
    #pragma unroll
    for (int j = 0; j < 4; ++j){
      p0[j] = (int)((((unsigned)bf16rne(hs0[j])) << 16) | 1u);
      p1[j] = (int)((((unsigned)bf16rne(hs1[j])) << 16) | 1u);
    }
    st128_c(H0 + SLOTB + (size_t)(eb*NH + ecol)*4, p0);
    st128_c(H1 + SLOTB + (size_t)(eb*NH + ecol)*4, p1);
  }

  __shared__ float scr[4][8][16][20];   // padded (proven)

  // per-wave gather base offset (row stride 4096 B; second half +65536)
  const size_t gofs = (size_t)l15*4096 + (size_t)wave*1024 + (size_t)l4*32;

  for (int p = 0; p <= T_SEQ; ++p){
    const bool doL0 = (p < T_SEQ);
    const bool doL1 = (p >= 1);

    // prefetch pre0 slice (plain cached load; consumed in epilogue)
    s16x4 praw = {0,0,0,0};
    if (doL0)
      praw = *(const s16x4*)(pre0 + (size_t)p*(NB*NH) + (size_t)eb*NH + ecol);

    f32x4 acc0[2][2] = {{{0,0,0,0},{0,0,0,0}},{{0,0,0,0},{0,0,0,0}}};
    f32x4 acc1[2][2] = {{{0,0,0,0},{0,0,0,0}},{{0,0,0,0},{0,0,0,0}}};

    // ---- h1(p-2): tag p. Gather, consume immediately (f1 dies here) ----
    if (doL1){
      const char* base = H1 + (size_t)((p-2)&1)*SLOTB + gofs;
      const unsigned tag = (unsigned)p;
      const unsigned rep = tag * 0x10001u;
      i32x4 f1[2][8];
      WAIT_GATHER(base, f1, rep, tag);
      #pragma unroll
      for (int cf = 0; cf < 2; ++cf)
        #pragma unroll
        for (int bt = 0; bt < 2; ++bt)
          #pragma unroll
          for (int s = 0; s < 8; ++s)
            acc1[cf][bt] = __builtin_amdgcn_mfma_f32_16x16x32_bf16(
                wA[2][cf][s], __builtin_bit_cast(bf16x8, f1[bt][s]), acc1[cf][bt], 0,0,0);
    }

    // ---- h0(p-1): tag p+1. Gather, consume for acc0 and acc1 ----
    {
      const char* base = H0 + (size_t)((p-1)&1)*SLOTB + gofs;
      const unsigned tag = (unsigned)(p + 1);
      const unsigned rep = tag * 0x10001u;
      i32x4 f0[2][8];
      WAIT_GATHER(base, f0, rep, tag);
      #pragma unroll
      for (int cf = 0; cf < 2; ++cf){
        #pragma unroll
        for (int bt = 0; bt < 2; ++bt){
          #pragma unroll
          for (int s = 0; s < 8; ++s){
            bf16x8 b0 = __builtin_bit_cast(bf16x8, f0[bt][s]);
            if (doL0)
              acc0[cf][bt] = __builtin_amdgcn_mfma_f32_16x16x32_bf16(wA[0][cf][s], b0, acc0[cf][bt], 0,0,0);
            if (doL1)
              acc1[cf][bt] = __builtin_amdgcn_mfma_f32_16x16x32_bf16(wA[1][cf][s], b0, acc1[cf][bt], 0,0,0);
          }
        }
      }
    }

    // ---- cross-wave K reduction via LDS (pre-write barrier restored:
    // per-wave slice validation does NOT prove sibling waves finished
    // their previous reduce reads — close the WAR window explicitly) ----
    __syncthreads();
    #pragma unroll
    for (int cf = 0; cf < 2; ++cf){
      #pragma unroll
      for (int bt = 0; bt < 2; ++bt){
        *(f32x4*)&scr[wave][(cf<<1)|bt][l15][l4*4]   = acc0[cf][bt];
        *(f32x4*)&scr[wave][4|(cf<<1)|bt][l15][l4*4] = acc1[cf][bt];
      }
    }
    __syncthreads();

    const int fL0 = ((ecb >> 2) << 1) | (eb >> 4);
    f32x4 s0v = {0,0,0,0}, s1v = {0,0,0,0};
    #pragma unroll
    for (int w = 0; w < 4; ++w){
      s0v += *(const f32x4*)&scr[w][fL0][eb & 15][(ecb & 3)*4];
      s1v += *(const f32x4*)&scr[w][4|fL0][eb & 15][(ecb & 3)*4];
    }

    // ---- activations; tagged state stores (NO drain, NO flag) ----
    const unsigned wtag0 = (unsigned)(p + 2);   // tagof(p)
    const unsigned wtag1 = (unsigned)(p + 1);   // tagof(p-1)
    float hv0[4], hv1[4];
    if (doL0){
      union { s16x4 v; _Float16 h[4]; } pu; pu.v = praw;
      i32x4 pk;
      #pragma unroll
      for (int j = 0; j < 4; ++j){
        hv0[j] = fast_tanh(s0v[j] + (float)pu.h[j]);
        pk[j] = (int)((((unsigned)bf16rne(hv0[j])) << 16) | wtag0);
      }
      st128_c(H0 + (size_t)(p&1)*SLOTB + (size_t)(eb*NH + ecol)*4, pk);
    }
    if (doL1){
      i32x4 pk;
      #pragma unroll
      for (int j = 0; j < 4; ++j){
        hv1[j] = fast_tanh(s1v[j] + bias1[j]);
        pk[j] = (int)((((unsigned)bf16rne(hv1[j])) << 16) | wtag1);
      }
      st128_c(H1 + (size_t)((p-1)&1)*SLOTB + (size_t)(eb*NH + ecol)*4, pk);
    }

    // ---- HBM outputs (plain stores, off the critical chain) ----
    if (doL1){
      f32x4 o = {hv1[0], hv1[1], hv1[2], hv1[3]};
      *(f32x4*)(dout + (size_t)(p-1)*(NB*NH) + (size_t)eb*NH + ecol) = o;
      if (p == T_SEQ)
        *(f32x4*)(dout + HIST_ELEMS + (size_t)NB*NH + (size_t)eb*NH + ecol) = o;
    }
    if (doL0 && p == T_SEQ-1){
      f32x4 o = {hv0[0], hv0[1], hv0[2], hv0[3]};
      *(f32x4*)(dout + HIST_ELEMS + (size_t)eb*NH + ecol) = o;
    }
  }
}

extern "C" void kernel_launch(void* const* d_in, const int* in_sizes, int n_in,
                              void* d_out, int out_size, void* d_ws, size_t ws_size,
                              hipStream_t stream)
{
  (void)in_sizes; (void)n_in; (void)out_size;
  const float* x   = (const float*)d_in[0];
  const float* h0  = (const float*)d_in[1];
  const float* Wih = (const float*)d_in[2];
  const float* Whh = (const float*)d_in[3];
  const float* bih = (const float*)d_in[4];
  const float* bhh = (const float*)d_in[5];
  float* out = (float*)d_out;
  char*  ws  = (char*)d_ws;

  const size_t PRE0_OFF = (size_t)1 << 20;
  const size_t NEED = PRE0_OFF + (size_t)T_SEQ*NB*NH*sizeof(_Float16);
  if (ws_size < NEED) return;

  _Float16* pre0 = (_Float16*)(ws + PRE0_OFF);

  // zero ALL tagged-state slots each launch: tag 0 = invalid
  hipMemsetAsync(ws, 0, 4096 + 4*(size_t)SLOTB, stream);
  pre_gemm<<<dim3(8, 512), 256, 0, stream>>>(x, Wih, bih, bhh, pre0);
  rnn_seq<<<dim3(TEAM), 256, 0, stream>>>(h0, Wih, Whh, bih, bhh, pre0, out, ws);
}